// Round 1
// baseline (557.906 us; speedup 1.0000x reference)
//
#include <hip/hip_runtime.h>
#include <hip/hip_bf16.h>

#define TOK 4096
#define HD 1024
#define ID 512
#define NE 64
#define TK 8
#define CAP 1024
#define NROUTE 32768   // TOK*TK
#define NCHUNK 128     // NROUTE/256

typedef __attribute__((ext_vector_type(4))) float f32x4;
typedef __attribute__((ext_vector_type(8))) short s16x8;

__device__ __forceinline__ ushort f2bf(float f){
  uint u = __builtin_bit_cast(uint, f);
  u += 0x7fffu + ((u >> 16) & 1u);
  return (ushort)(u >> 16);
}
__device__ __forceinline__ float bf2f(ushort b){
  uint u = ((uint)b) << 16;
  return __builtin_bit_cast(float, u);
}

// ---------------- gating: fp64-accurate scores + top-8 + normalized weights --
__global__ __launch_bounds__(256)
void gating_kernel(const float* __restrict__ X, const float* __restrict__ GW,
                   int* __restrict__ topi, float* __restrict__ topw)
{
  __shared__ float xt[64][33];
  __shared__ float gt[64][33];
  __shared__ double ds[64][65];
  const int tid = threadIdx.x;
  const int tbase = blockIdx.x * 64;
  const int tok = tid >> 2, eg = (tid & 3) * 16;
  double acc[16];
  #pragma unroll
  for (int j=0;j<16;++j) acc[j]=0.0;
  for (int hc=0; hc<HD; hc+=32){
    #pragma unroll
    for (int it=0; it<2; ++it){
      int idx = it*256 + tid;
      int r = idx >> 3, c4 = (idx & 7)*4;
      *(float4*)&xt[r][c4] = *(const float4*)(X + (size_t)(tbase+r)*HD + hc + c4);
      *(float4*)&gt[r][c4] = *(const float4*)(GW + (size_t)r*HD + hc + c4);
    }
    __syncthreads();
    #pragma unroll
    for (int h=0; h<32; ++h){
      double xv = (double)xt[tok][h];
      #pragma unroll
      for (int j=0;j<16;++j) acc[j] += xv * (double)gt[eg+j][h];
    }
    __syncthreads();
  }
  #pragma unroll
  for (int j=0;j<16;++j) ds[tok][eg+j] = acc[j];
  __syncthreads();
  if (tid < 64){
    int t = tid;
    int idxs[8]; double vals[8]; double sum = 0.0;
    #pragma unroll
    for (int k=0;k<8;++k){
      double best = -1e300; int bi = 0;
      for (int e=0;e<NE;++e){ double v = ds[t][e]; if (v > best){ best = v; bi = e; } }
      ds[t][bi] = -1e300;
      double w = 1.0 / (1.0 + exp(-best));
      idxs[k] = bi; vals[k] = w; sum += w;
    }
    double inv = 1.0 / sum;
    #pragma unroll
    for (int k=0;k<8;++k){
      topi[(size_t)(tbase+t)*TK + k] = idxs[k];
      topw[(size_t)(tbase+t)*TK + k] = (float)(vals[k]*inv);
    }
  }
}

// ---------------- dispatch bookkeeping ---------------------------------------
__global__ __launch_bounds__(256)
void hist_kernel(const int* __restrict__ topi, int* __restrict__ ccnt){
  __shared__ int h[NE];
  const int tid = threadIdx.x;
  if (tid < NE) h[tid] = 0;
  __syncthreads();
  atomicAdd(&h[topi[blockIdx.x*256 + tid]], 1);
  __syncthreads();
  if (tid < NE) ccnt[blockIdx.x*NE + tid] = h[tid];
}

__global__ __launch_bounds__(64)
void scan_kernel(const int* __restrict__ ccnt, int* __restrict__ cbase,
                 int* __restrict__ cntC, int* __restrict__ ebase){
  const int e = threadIdx.x;
  int run = 0;
  for (int c=0;c<NCHUNK;++c){ cbase[c*NE+e] = run; run += ccnt[c*NE+e]; }
  cntC[e] = run < CAP ? run : CAP;
  __syncthreads();
  if (e == 0){
    int s = 0;
    for (int i=0;i<NE;++i){ ebase[i] = s; s += cntC[i]; }
    ebase[NE] = s;
  }
}

__global__ __launch_bounds__(64)
void assign_kernel(const int* __restrict__ topi, const int* __restrict__ cbase,
                   int* __restrict__ pos, int* __restrict__ rowlist){
  __shared__ int es[256];
  const int tid = threadIdx.x;
  const int c = blockIdx.x;
  for (int i=tid;i<256;i+=64) es[i] = topi[c*256+i];
  __syncthreads();
  const int e = tid;
  int cntr = cbase[c*NE+e];
  for (int j=0;j<256;++j){
    if (es[j] == e){
      int n = c*256+j;
      pos[n] = cntr;
      if (cntr < CAP) rowlist[e*CAP + cntr] = n;
      ++cntr;
    }
  }
}

// ---------------- grouped gate/up GEMM + fused SwiGLU ------------------------
// tile: 128 rows x 64 i-cols, K-chunk 64.  Output: interm[row][i] bf16.
template<bool SHARED>
__global__ __launch_bounds__(256,2)
void gateup_kernel(const float* __restrict__ X, const float* __restrict__ WG,
                   const float* __restrict__ WU, const int* __restrict__ rowlist,
                   const int* __restrict__ cntC, const int* __restrict__ ebase,
                   ushort* __restrict__ interm)
{
  int e, mt, nt, cnt, outbase;
  if (SHARED){
    nt = blockIdx.x & 7; mt = blockIdx.x >> 3; e = 0; cnt = TOK; outbase = mt*128;
  } else {
    int x = blockIdx.x & 7; int rem = blockIdx.x >> 3;
    nt = rem & 7; mt = (rem >> 3) & 7; e = ((rem >> 6) << 3) | x;  // e%8 == bid%8 -> XCD locality
    cnt = cntC[e];
    if (mt*128 >= cnt) return;
    outbase = ebase[e] + mt*128;
  }
  const size_t wof = SHARED ? 0 : (size_t)e*ID*HD;
  const float* wg = WG + wof + (size_t)nt*64*HD;
  const float* wu = WU + wof + (size_t)nt*64*HD;

  __shared__ ushort aL[128][72];
  __shared__ ushort gL[64][72];
  __shared__ ushort uL[64][72];
  __shared__ int tokb[128];

  const int tid = threadIdx.x;
  if (tid < 128){
    int tokv;
    if (SHARED) tokv = mt*128 + tid;
    else tokv = (mt*128 + tid < cnt) ? (rowlist[e*CAP + mt*128 + tid] >> 3) : 0;
    tokb[tid] = tokv;
  }
  __syncthreads();

  f32x4 accg[2][4], accu[2][4];
  #pragma unroll
  for (int i=0;i<2;++i)
    #pragma unroll
    for (int j=0;j<4;++j){ accg[i][j] = (f32x4)0.0f; accu[i][j] = (f32x4)0.0f; }

  const int w = tid >> 6, l = tid & 63;
  const int fr = l & 15, fko = (l >> 4) * 8;

  for (int kc=0; kc<HD; kc+=64){
    #pragma unroll
    for (int it=0; it<8; ++it){
      int idx = it*256 + tid;
      int r = idx >> 4, c4 = (idx & 15) * 4;
      float4 v = *(const float4*)(X + (size_t)tokb[r]*HD + kc + c4);
      ushort4 b; b.x=f2bf(v.x); b.y=f2bf(v.y); b.z=f2bf(v.z); b.w=f2bf(v.w);
      *(ushort4*)&aL[r][c4] = b;
    }
    #pragma unroll
    for (int it=0; it<4; ++it){
      int idx = it*256 + tid;
      int r = idx >> 4, c4 = (idx & 15) * 4;
      float4 v = *(const float4*)(wg + (size_t)r*HD + kc + c4);
      ushort4 b; b.x=f2bf(v.x); b.y=f2bf(v.y); b.z=f2bf(v.z); b.w=f2bf(v.w);
      *(ushort4*)&gL[r][c4] = b;
      v = *(const float4*)(wu + (size_t)r*HD + kc + c4);
      b.x=f2bf(v.x); b.y=f2bf(v.y); b.z=f2bf(v.z); b.w=f2bf(v.w);
      *(ushort4*)&uL[r][c4] = b;
    }
    __syncthreads();
    #pragma unroll
    for (int ks=0; ks<2; ++ks){
      s16x8 a0 = *(const s16x8*)&aL[w*32 + fr][ks*32 + fko];
      s16x8 a1 = *(const s16x8*)&aL[w*32 + 16 + fr][ks*32 + fko];
      #pragma unroll
      for (int cg=0; cg<4; ++cg){
        s16x8 bg = *(const s16x8*)&gL[cg*16 + fr][ks*32 + fko];
        s16x8 bu = *(const s16x8*)&uL[cg*16 + fr][ks*32 + fko];
        accg[0][cg] = __builtin_amdgcn_mfma_f32_16x16x32_bf16(a0, bg, accg[0][cg], 0, 0, 0);
        accg[1][cg] = __builtin_amdgcn_mfma_f32_16x16x32_bf16(a1, bg, accg[1][cg], 0, 0, 0);
        accu[0][cg] = __builtin_amdgcn_mfma_f32_16x16x32_bf16(a0, bu, accu[0][cg], 0, 0, 0);
        accu[1][cg] = __builtin_amdgcn_mfma_f32_16x16x32_bf16(a1, bu, accu[1][cg], 0, 0, 0);
      }
    }
    __syncthreads();
  }

  const int rq = (l >> 4) * 4;
  #pragma unroll
  for (int rg=0; rg<2; ++rg){
    #pragma unroll
    for (int q=0; q<4; ++q){
      int rl = mt*128 + w*32 + rg*16 + rq + q;
      if (!SHARED && rl >= cnt) continue;
      size_t orow = (size_t)(outbase + w*32 + rg*16 + rq + q);
      #pragma unroll
      for (int cg=0; cg<4; ++cg){
        float g = accg[rg][cg][q], u = accu[rg][cg][q];
        float sv = g / (1.0f + __expf(-g)) * u;   // silu(g)*u
        interm[orow*ID + (size_t)nt*64 + cg*16 + fr] = f2bf(sv);
      }
    }
  }
}

// ---------------- grouped down GEMM ------------------------------------------
template<bool SHARED>
__global__ __launch_bounds__(256,2)
void down_kernel(const ushort* __restrict__ interm, const float* __restrict__ WD,
                 const int* __restrict__ cntC, const int* __restrict__ ebase,
                 ushort* __restrict__ out_rows, float* __restrict__ outf)
{
  int e, mt, nt, cnt, abase;
  if (SHARED){
    nt = blockIdx.x & 15; mt = blockIdx.x >> 4; e = 0; cnt = TOK; abase = mt*128;
  } else {
    int x = blockIdx.x & 7; int rem = blockIdx.x >> 3;
    nt = rem & 15; mt = (rem >> 4) & 7; e = ((rem >> 7) << 3) | x;
    cnt = cntC[e];
    if (mt*128 >= cnt) return;
    abase = ebase[e] + mt*128;
  }
  const ushort* A = interm + (size_t)abase*ID;
  const float* wd = WD + (SHARED ? (size_t)0 : (size_t)e*HD*ID) + (size_t)nt*64*ID;

  __shared__ ushort aL[128][72];
  __shared__ ushort dL[64][72];

  const int tid = threadIdx.x;
  const int w = tid >> 6, l = tid & 63;
  const int fr = l & 15, fko = (l >> 4) * 8;

  f32x4 acc[2][4];
  #pragma unroll
  for (int i=0;i<2;++i)
    #pragma unroll
    for (int j=0;j<4;++j) acc[i][j] = (f32x4)0.0f;

  for (int kc=0; kc<ID; kc+=64){
    #pragma unroll
    for (int it=0; it<4; ++it){
      int idx = it*256 + tid;
      int r = idx >> 3, c8 = (idx & 7) * 8;
      *(uint4*)&aL[r][c8] = *(const uint4*)(A + (size_t)r*ID + kc + c8);
    }
    #pragma unroll
    for (int it=0; it<4; ++it){
      int idx = it*256 + tid;
      int r = idx >> 4, c4 = (idx & 15) * 4;
      float4 v = *(const float4*)(wd + (size_t)r*ID + kc + c4);
      ushort4 b; b.x=f2bf(v.x); b.y=f2bf(v.y); b.z=f2bf(v.z); b.w=f2bf(v.w);
      *(ushort4*)&dL[r][c4] = b;
    }
    __syncthreads();
    #pragma unroll
    for (int ks=0; ks<2; ++ks){
      s16x8 a0 = *(const s16x8*)&aL[w*32 + fr][ks*32 + fko];
      s16x8 a1 = *(const s16x8*)&aL[w*32 + 16 + fr][ks*32 + fko];
      #pragma unroll
      for (int cg=0; cg<4; ++cg){
        s16x8 bd = *(const s16x8*)&dL[cg*16 + fr][ks*32 + fko];
        acc[0][cg] = __builtin_amdgcn_mfma_f32_16x16x32_bf16(a0, bd, acc[0][cg], 0, 0, 0);
        acc[1][cg] = __builtin_amdgcn_mfma_f32_16x16x32_bf16(a1, bd, acc[1][cg], 0, 0, 0);
      }
    }
    __syncthreads();
  }

  const int rq = (l >> 4) * 4;
  #pragma unroll
  for (int rg=0; rg<2; ++rg){
    #pragma unroll
    for (int q=0; q<4; ++q){
      int rl = mt*128 + w*32 + rg*16 + rq + q;
      if (!SHARED && rl >= cnt) continue;
      int row = w*32 + rg*16 + rq + q;
      #pragma unroll
      for (int cg=0; cg<4; ++cg){
        float v = acc[rg][cg][q];
        int colg = nt*64 + cg*16 + fr;
        if (SHARED) outf[(size_t)(mt*128 + row)*HD + colg] = v;
        else        out_rows[(size_t)(abase + row)*HD + colg] = f2bf(v);
      }
    }
  }
}

// ---------------- combine: out += sum_k topw * routed_row --------------------
__global__ __launch_bounds__(256)
void combine_kernel(const int* __restrict__ topi, const float* __restrict__ topw,
                    const int* __restrict__ pos, const int* __restrict__ ebase,
                    const ushort* __restrict__ out_rows, float* __restrict__ out)
{
  const int t = blockIdx.x;
  const int tid = threadIdx.x;
  __shared__ int rws[TK];
  __shared__ float wts[TK];
  if (tid < TK){
    int e = topi[(size_t)t*TK + tid];
    int p = pos[(size_t)t*TK + tid];
    rws[tid] = (p < CAP) ? (ebase[e] + p) : -1;
    wts[tid] = topw[(size_t)t*TK + tid];
  }
  __syncthreads();
  const int h0 = tid * 4;
  float4 acc = *(float4*)(out + (size_t)t*HD + h0);
  #pragma unroll
  for (int k=0;k<TK;++k){
    int r = rws[k];
    if (r < 0) continue;
    ushort4 v = *(const ushort4*)(out_rows + (size_t)r*HD + h0);
    float wk = wts[k];
    acc.x += wk*bf2f(v.x); acc.y += wk*bf2f(v.y);
    acc.z += wk*bf2f(v.z); acc.w += wk*bf2f(v.w);
  }
  *(float4*)(out + (size_t)t*HD + h0) = acc;
}

// ---------------- launch ------------------------------------------------------
extern "C" void kernel_launch(void* const* d_in, const int* in_sizes, int n_in,
                              void* d_out, int out_size, void* d_ws, size_t ws_size,
                              hipStream_t stream)
{
  (void)in_sizes; (void)n_in; (void)out_size; (void)ws_size;
  const float* X   = (const float*)d_in[0];
  const float* GW  = (const float*)d_in[1];
  const float* SWG = (const float*)d_in[2];
  const float* SWU = (const float*)d_in[3];
  const float* SWD = (const float*)d_in[4];
  const float* EWG = (const float*)d_in[5];
  const float* EWU = (const float*)d_in[6];
  const float* EWD = (const float*)d_in[7];
  float* OUT = (float*)d_out;

  char* p = (char*)d_ws;
  int*    topi    = (int*)p;      p += (size_t)NROUTE*4;
  float*  topw    = (float*)p;    p += (size_t)NROUTE*4;
  int*    pos     = (int*)p;      p += (size_t)NROUTE*4;
  int*    ccnt    = (int*)p;      p += (size_t)NCHUNK*NE*4;
  int*    cbase   = (int*)p;      p += (size_t)NCHUNK*NE*4;
  int*    cntC    = (int*)p;      p += 256;
  int*    ebase   = (int*)p;      p += 512;
  int*    rowlist = (int*)p;      p += (size_t)NE*CAP*4;
  ushort* interm_r= (ushort*)p;   p += (size_t)(NROUTE+128)*ID*2;
  ushort* interm_s= (ushort*)p;   p += (size_t)TOK*ID*2;
  ushort* out_rows= (ushort*)p;   p += (size_t)NROUTE*HD*2;

  gating_kernel<<<64, 256, 0, stream>>>(X, GW, topi, topw);
  hist_kernel<<<NCHUNK, 256, 0, stream>>>(topi, ccnt);
  scan_kernel<<<1, 64, 0, stream>>>(ccnt, cbase, cntC, ebase);
  assign_kernel<<<NCHUNK, 64, 0, stream>>>(topi, cbase, pos, rowlist);

  gateup_kernel<false><<<4096, 256, 0, stream>>>(X, EWG, EWU, rowlist, cntC, ebase, interm_r);
  gateup_kernel<true ><<<256,  256, 0, stream>>>(X, SWG, SWU, nullptr, nullptr, nullptr, interm_s);
  down_kernel<false><<<8192, 256, 0, stream>>>(interm_r, EWD, cntC, ebase, out_rows, nullptr);
  down_kernel<true ><<<512,  256, 0, stream>>>(interm_s, SWD, nullptr, nullptr, nullptr, OUT);

  combine_kernel<<<TOK, 256, 0, stream>>>(topi, topw, pos, ebase, out_rows, OUT);
}